// Round 2
// baseline (283.709 us; speedup 1.0000x reference)
//
#include <hip/hip_runtime.h>
#include <stdint.h>

#define EMBED 768
#define HD 64
#define SEQ 4096
#define BATCH 4
#define NROW (BATCH * SEQ)  // 16384

typedef __bf16 bf16x8 __attribute__((ext_vector_type(8)));
typedef float f32x4 __attribute__((ext_vector_type(4)));

__device__ __forceinline__ unsigned short f2bf(float f) {
    unsigned int u = __float_as_uint(f);
    u += 0x7fffu + ((u >> 16) & 1u);   // round-to-nearest-even
    return (unsigned short)(u >> 16);
}

// ---------------- fused QKV projection ----------------
// grid: (NROW/64, 3), block: 256 (4 waves). Each block: 64x64 output tile of one matrix.
// Outputs: q, k row-major [NROW][64] bf16;  v transposed [64][NROW] bf16.
__global__ __launch_bounds__(256)
void qkv_proj_kernel(const float* __restrict__ hidden,
                     const float* __restrict__ Wq, const float* __restrict__ bq,
                     const float* __restrict__ Wk, const float* __restrict__ bk,
                     const float* __restrict__ Wv, const float* __restrict__ bv,
                     unsigned short* __restrict__ qo,
                     unsigned short* __restrict__ ko,
                     unsigned short* __restrict__ vto) {
    __shared__ __attribute__((aligned(16))) unsigned short hs[64][72]; // +8 pad: 2-way banks only
    __shared__ __attribute__((aligned(16))) unsigned short wt[64][72]; // W tile transposed [col][k]

    const int mat = blockIdx.y;
    const int m0  = blockIdx.x * 64;
    const float* W    = (mat == 0) ? Wq : (mat == 1) ? Wk : Wv;
    const float* bias = (mat == 0) ? bq : (mat == 1) ? bk : bv;

    const int t    = threadIdx.x;
    const int wave = t >> 6;
    const int lane = t & 63;
    const int lr   = lane & 15;
    const int lg   = lane >> 4;

    f32x4 acc[4];
    const f32x4 zero4 = {0.f, 0.f, 0.f, 0.f};
    #pragma unroll
    for (int n = 0; n < 4; ++n) acc[n] = zero4;

    const int rr = t >> 4;        // 0..15
    const int c4 = (t & 15) * 4;  // 0..60

    for (int k0 = 0; k0 < EMBED; k0 += 64) {
        #pragma unroll
        for (int pass = 0; pass < 4; ++pass) {
            const int r = rr + pass * 16;
            // hidden tile [64 rows][64 k] -> bf16 LDS (coalesced float4)
            float4 hv = *(const float4*)&hidden[(size_t)(m0 + r) * EMBED + k0 + c4];
            ushort4 pk;
            pk.x = f2bf(hv.x); pk.y = f2bf(hv.y); pk.z = f2bf(hv.z); pk.w = f2bf(hv.w);
            *(ushort4*)&hs[r][c4] = pk;
            // W tile [64 k][64 cols] -> transposed LDS wt[col][k]
            float4 wv = *(const float4*)&W[(size_t)(k0 + r) * HD + c4];
            wt[c4 + 0][r] = f2bf(wv.x);
            wt[c4 + 1][r] = f2bf(wv.y);
            wt[c4 + 2][r] = f2bf(wv.z);
            wt[c4 + 3][r] = f2bf(wv.w);
        }
        __syncthreads();
        #pragma unroll
        for (int ks = 0; ks < 2; ++ks) {
            bf16x8 a = *(const bf16x8*)&hs[wave * 16 + lr][ks * 32 + lg * 8];
            #pragma unroll
            for (int n = 0; n < 4; ++n) {
                bf16x8 bb = *(const bf16x8*)&wt[n * 16 + lr][ks * 32 + lg * 8];
                acc[n] = __builtin_amdgcn_mfma_f32_16x16x32_bf16(a, bb, acc[n], 0, 0, 0);
            }
        }
        __syncthreads();
    }

    // epilogue: +bias, convert bf16, store
    const int row0 = m0 + wave * 16 + lg * 4;  // C/D: row=(lane>>4)*4+reg, col=lane&15
    if (mat < 2) {
        unsigned short* out = (mat == 0) ? qo : ko;
        #pragma unroll
        for (int n = 0; n < 4; ++n) {
            const float bb = bias[n * 16 + lr];
            #pragma unroll
            for (int r = 0; r < 4; ++r)
                out[(size_t)(row0 + r) * HD + n * 16 + lr] = f2bf(acc[n][r] + bb);
        }
    } else {
        #pragma unroll
        for (int n = 0; n < 4; ++n) {
            const float bb = bias[n * 16 + lr];
            ushort4 pk;
            pk.x = f2bf(acc[n][0] + bb);
            pk.y = f2bf(acc[n][1] + bb);
            pk.z = f2bf(acc[n][2] + bb);
            pk.w = f2bf(acc[n][3] + bb);
            *(ushort4*)&vto[(size_t)(n * 16 + lr) * NROW + row0] = pk; // 4 consecutive rows
        }
    }
}

// ---------------- causal flash attention ----------------
// grid: 1024 blocks x 64 threads; block = one wave = one 16-row Q strip.
// b = bid&3 (batch fastest, balances per-CU causal work), strip = bid>>2.
__global__ __launch_bounds__(64)
void attn_kernel(const unsigned short* __restrict__ qg,
                 const unsigned short* __restrict__ kg,
                 const unsigned short* __restrict__ vtg,
                 float* __restrict__ out) {
    __shared__ __attribute__((aligned(16))) unsigned short p_lds[16][40]; // stride 80B: 2-way banks

    const int bid = blockIdx.x;
    const int b   = bid & 3;
    const int q0  = (bid >> 2) * 16;
    const int lane = threadIdx.x;
    const int lr   = lane & 15;
    const int lg   = lane >> 4;

    const unsigned short* qb  = qg  + (size_t)b * SEQ * HD;
    const unsigned short* kbp = kg  + (size_t)b * SEQ * HD;
    const unsigned short* vb  = vtg + (size_t)b * SEQ;   // vb[d*NROW + s]

    // Q fragments: row q0+lr, 8 consecutive d at (lg*8) and (32+lg*8)
    const bf16x8 qf0 = *(const bf16x8*)&qb[(q0 + lr) * HD + lg * 8];
    const bf16x8 qf1 = *(const bf16x8*)&qb[(q0 + lr) * HD + 32 + lg * 8];

    f32x4 acc[4];
    const f32x4 zero4 = {0.f, 0.f, 0.f, 0.f};
    #pragma unroll
    for (int n = 0; n < 4; ++n) acc[n] = zero4;
    float m[4], lsum[4];
    #pragma unroll
    for (int r = 0; r < 4; ++r) { m[r] = -INFINITY; lsum[r] = 0.f; }

    const float sc = 0.18033688011112042f; // log2(e) / sqrt(64)  -> softmax in exp2 domain

    const int kend = q0 + 16;
    for (int kb0 = 0; kb0 < kend; kb0 += 32) {
        // K^T B-fragments: col=key, 8 consecutive d (row-major K is already the right layout)
        bf16x8 k00 = *(const bf16x8*)&kbp[(kb0 + lr) * HD + lg * 8];
        bf16x8 k01 = *(const bf16x8*)&kbp[(kb0 + lr) * HD + 32 + lg * 8];
        bf16x8 k10 = *(const bf16x8*)&kbp[(kb0 + 16 + lr) * HD + lg * 8];
        bf16x8 k11 = *(const bf16x8*)&kbp[(kb0 + 16 + lr) * HD + 32 + lg * 8];

        f32x4 s0 = zero4, s1 = zero4;
        s0 = __builtin_amdgcn_mfma_f32_16x16x32_bf16(qf0, k00, s0, 0, 0, 0);
        s0 = __builtin_amdgcn_mfma_f32_16x16x32_bf16(qf1, k01, s0, 0, 0, 0);
        s1 = __builtin_amdgcn_mfma_f32_16x16x32_bf16(qf0, k10, s1, 0, 0, 0);
        s1 = __builtin_amdgcn_mfma_f32_16x16x32_bf16(qf1, k11, s1, 0, 0, 0);

        float t0[4], t1[4];
        #pragma unroll
        for (int r = 0; r < 4; ++r) { t0[r] = s0[r] * sc; t1[r] = s1[r] * sc; }

        if (kb0 + 31 > q0) {  // diagonal tile: causal mask (key > query -> -inf)
            #pragma unroll
            for (int r = 0; r < 4; ++r) {
                const int qr = q0 + lg * 4 + r;
                if (kb0 + lr > qr)      t0[r] = -1e30f;
                if (kb0 + 16 + lr > qr) t1[r] = -1e30f;
            }
        }

        // row max over 32 keys: lane-local pair + xor-reduce across 16-lane group
        float mx[4];
        #pragma unroll
        for (int r = 0; r < 4; ++r) mx[r] = fmaxf(t0[r], t1[r]);
        #pragma unroll
        for (int off = 1; off < 16; off <<= 1) {
            #pragma unroll
            for (int r = 0; r < 4; ++r) mx[r] = fmaxf(mx[r], __shfl_xor(mx[r], off));
        }

        float p0[4], p1[4], rs[4], so[4];
        #pragma unroll
        for (int r = 0; r < 4; ++r) {
            const float nm = fmaxf(m[r], mx[r]);
            so[r] = __builtin_exp2f(m[r] - nm);   // m=-inf first iter -> 0
            m[r]  = nm;
            p0[r] = __builtin_exp2f(t0[r] - nm);  // masked -1e30 -> 0
            p1[r] = __builtin_exp2f(t1[r] - nm);
            rs[r] = p0[r] + p1[r];
        }
        #pragma unroll
        for (int off = 1; off < 16; off <<= 1) {
            #pragma unroll
            for (int r = 0; r < 4; ++r) rs[r] += __shfl_xor(rs[r], off);
        }
        #pragma unroll
        for (int r = 0; r < 4; ++r) lsum[r] = lsum[r] * so[r] + rs[r];
        #pragma unroll
        for (int n = 0; n < 4; ++n)
            #pragma unroll
            for (int r = 0; r < 4; ++r) acc[n][r] *= so[r];

        // P (16x32) -> LDS in bf16, re-read in A-fragment layout
        #pragma unroll
        for (int r = 0; r < 4; ++r) {
            p_lds[lg * 4 + r][lr]      = f2bf(p0[r]);
            p_lds[lg * 4 + r][16 + lr] = f2bf(p1[r]);
        }
        __syncthreads();
        const bf16x8 pa = *(const bf16x8*)&p_lds[lr][lg * 8];
        #pragma unroll
        for (int n = 0; n < 4; ++n) {
            bf16x8 vf = *(const bf16x8*)&vb[(size_t)(n * 16 + lr) * NROW + kb0 + lg * 8];
            acc[n] = __builtin_amdgcn_mfma_f32_16x16x32_bf16(pa, vf, acc[n], 0, 0, 0);
        }
        __syncthreads();
    }

    float inv[4];
    #pragma unroll
    for (int r = 0; r < 4; ++r) inv[r] = 1.0f / lsum[r];
    #pragma unroll
    for (int n = 0; n < 4; ++n)
        #pragma unroll
        for (int r = 0; r < 4; ++r)
            out[((size_t)b * SEQ + q0 + lg * 4 + r) * HD + n * 16 + lr] = acc[n][r] * inv[r];
}

extern "C" void kernel_launch(void* const* d_in, const int* in_sizes, int n_in,
                              void* d_out, int out_size, void* d_ws, size_t ws_size,
                              hipStream_t stream) {
    const float* hidden = (const float*)d_in[0];
    const float* Wq = (const float*)d_in[1];
    const float* bq = (const float*)d_in[2];
    const float* Wk = (const float*)d_in[3];
    const float* bk = (const float*)d_in[4];
    const float* Wv = (const float*)d_in[5];
    const float* bv = (const float*)d_in[6];

    unsigned short* qbuf = (unsigned short*)d_ws;          // [NROW][64] bf16
    unsigned short* kbuf = qbuf + (size_t)NROW * HD;       // [NROW][64] bf16
    unsigned short* vtbuf = kbuf + (size_t)NROW * HD;      // [64][NROW] bf16 (V transposed)

    qkv_proj_kernel<<<dim3(NROW / 64, 3), 256, 0, stream>>>(
        hidden, Wq, bq, Wk, bk, Wv, bv, qbuf, kbuf, vtbuf);

    attn_kernel<<<dim3(BATCH * SEQ / 16), 64, 0, stream>>>(
        qbuf, kbuf, vtbuf, (float*)d_out);
}

// Round 3
// 207.573 us; speedup vs baseline: 1.3668x; 1.3668x over previous
//
#include <hip/hip_runtime.h>
#include <stdint.h>

#define EMBED 768
#define HD 64
#define SEQ 4096
#define BATCH 4
#define NROW (BATCH * SEQ)   // 16384
#define NSTRIP (NROW / 16)   // 1024
#define KSPLIT 4

typedef __bf16 bf16x8 __attribute__((ext_vector_type(8)));
typedef __bf16 bf16x4 __attribute__((ext_vector_type(4)));
typedef float f32x4 __attribute__((ext_vector_type(4)));

// ---------------- W -> wT [192][768] bf16 (once, tiny) ----------------
__global__ __launch_bounds__(256)
void wconv_kernel(const float* __restrict__ Wq, const float* __restrict__ Wk,
                  const float* __restrict__ Wv, __bf16* __restrict__ wT) {
    int id = blockIdx.x * 256 + threadIdx.x;   // < 192*768
    int c = id / EMBED, k = id - c * EMBED;
    const float* W = (c < 64) ? Wq : (c < 128) ? Wk : Wv;
    wT[id] = (__bf16)W[(size_t)k * HD + (c & 63)];
}

// ---------------- fused QKV GEMM: no LDS, register-direct ----------------
// grid: NROW/16 = 1024 blocks x 64 thr. Wave = 16 rows x 192 cols (Q|K|V).
// A: hidden f32 from global + cvt; B: wT bf16 from global (L2-resident).
__global__ __launch_bounds__(64)
void qkv_gemm_kernel(const float* __restrict__ hidden, const __bf16* __restrict__ wT,
                     const float* __restrict__ bq, const float* __restrict__ bk,
                     const float* __restrict__ bv,
                     __bf16* __restrict__ qo, __bf16* __restrict__ ko,
                     __bf16* __restrict__ vto) {
    const int m0 = blockIdx.x * 16;
    const int lane = threadIdx.x, lr = lane & 15, lg = lane >> 4;

    f32x4 acc[12];
    #pragma unroll
    for (int n = 0; n < 12; ++n) acc[n] = (f32x4){0.f, 0.f, 0.f, 0.f};

    const float* hrow = hidden + (size_t)(m0 + lr) * EMBED + lg * 8;
    const __bf16* wbase = wT + lg * 8;

    for (int k0 = 0; k0 < EMBED; k0 += 64) {
        bf16x8 a[2];
        #pragma unroll
        for (int ks = 0; ks < 2; ++ks) {
            float4 h0 = *(const float4*)(hrow + k0 + ks * 32);
            float4 h1 = *(const float4*)(hrow + k0 + ks * 32 + 4);
            bf16x8 t;
            t[0] = (__bf16)h0.x; t[1] = (__bf16)h0.y; t[2] = (__bf16)h0.z; t[3] = (__bf16)h0.w;
            t[4] = (__bf16)h1.x; t[5] = (__bf16)h1.y; t[6] = (__bf16)h1.z; t[7] = (__bf16)h1.w;
            a[ks] = t;
        }
        #pragma unroll
        for (int n = 0; n < 12; ++n) {
            #pragma unroll
            for (int ks = 0; ks < 2; ++ks) {
                bf16x8 bb = *(const bf16x8*)(wbase + (size_t)(n * 16 + lr) * EMBED + k0 + ks * 32);
                acc[n] = __builtin_amdgcn_mfma_f32_16x16x32_bf16(a[ks], bb, acc[n], 0, 0, 0);
            }
        }
    }

    // epilogue: +bias, store q/k row-major, v transposed
    const int row0 = m0 + lg * 4;   // C/D: row=(lane>>4)*4+r, col=n*16+lr
    #pragma unroll
    for (int n = 0; n < 4; ++n) {
        const float b1 = bq[n * 16 + lr];
        const float b2 = bk[n * 16 + lr];
        const float b3 = bv[n * 16 + lr];
        #pragma unroll
        for (int r = 0; r < 4; ++r) {
            qo[(size_t)(row0 + r) * HD + n * 16 + lr] = (__bf16)(acc[n][r] + b1);
            ko[(size_t)(row0 + r) * HD + n * 16 + lr] = (__bf16)(acc[n + 4][r] + b2);
        }
        bf16x4 pv;
        pv[0] = (__bf16)(acc[n + 8][0] + b3);
        pv[1] = (__bf16)(acc[n + 8][1] + b3);
        pv[2] = (__bf16)(acc[n + 8][2] + b3);
        pv[3] = (__bf16)(acc[n + 8][3] + b3);
        *(bf16x4*)&vto[(size_t)(n * 16 + lr) * NROW + row0] = pv;  // 4 consecutive rows
    }
}

// ---------------- causal flash attention, split-K partials ----------------
// grid: NSTRIP*KSPLIT blocks x 64 thr (1 wave). Longest strips dispatched first.
// Each block: 16 Q rows x keys [split*chunk, min(+chunk, q0+16)), KBLK=64.
// Writes unnormalized O partial + per-row (m, l) to ws.
__global__ __launch_bounds__(64)
void attn_kernel(const __bf16* __restrict__ qg, const __bf16* __restrict__ kg,
                 const __bf16* __restrict__ vtg,
                 float* __restrict__ opart, float* __restrict__ ml) {
    __shared__ __bf16 p_lds[16][72];   // 144B row stride: 2-way banks (free)

    const int bid   = blockIdx.x;
    const int s     = (NSTRIP - 1) - (bid >> 2);   // descending work
    const int split = bid & 3;
    const int b     = s & 3;
    const int q0    = (s >> 2) * 16;
    const int lane = threadIdx.x, lr = lane & 15, lg = lane >> 4;

    const int nk    = q0 + 16;
    const int chunk = ((nk + KSPLIT * 64 - 1) / (KSPLIT * 64)) * 64;
    const int kb    = split * chunk;
    const int ke    = (kb + chunk < nk) ? (kb + chunk) : nk;

    float* mlp = ml + ((size_t)s * KSPLIT + split) * 32;
    if (kb >= ke) {             // empty split: mark l=0, done
        if (lane < 16) mlp[16 + lane] = 0.f;
        return;
    }

    const __bf16* qb = qg  + (size_t)b * SEQ * HD;
    const __bf16* kp = kg  + (size_t)b * SEQ * HD;
    const __bf16* vb = vtg + (size_t)b * SEQ;   // vb[d*NROW + key]

    const bf16x8 qf0 = *(const bf16x8*)&qb[(q0 + lr) * HD + lg * 8];
    const bf16x8 qf1 = *(const bf16x8*)&qb[(q0 + lr) * HD + 32 + lg * 8];

    f32x4 acc[4];
    const f32x4 zero4 = {0.f, 0.f, 0.f, 0.f};
    #pragma unroll
    for (int n = 0; n < 4; ++n) acc[n] = zero4;
    float m[4], lsum[4];
    #pragma unroll
    for (int r = 0; r < 4; ++r) { m[r] = -INFINITY; lsum[r] = 0.f; }

    const float sc = 0.18033688011112042f;  // log2(e)/sqrt(64): softmax in exp2 domain

    for (int kb0 = kb; kb0 < ke; kb0 += 64) {
        // QK^T for 64 keys (4 x 16-key column tiles)
        f32x4 sj[4];
        #pragma unroll
        for (int j = 0; j < 4; ++j) {
            bf16x8 kf0 = *(const bf16x8*)&kp[(size_t)(kb0 + j * 16 + lr) * HD + lg * 8];
            bf16x8 kf1 = *(const bf16x8*)&kp[(size_t)(kb0 + j * 16 + lr) * HD + 32 + lg * 8];
            f32x4 z = zero4;
            z = __builtin_amdgcn_mfma_f32_16x16x32_bf16(qf0, kf0, z, 0, 0, 0);
            z = __builtin_amdgcn_mfma_f32_16x16x32_bf16(qf1, kf1, z, 0, 0, 0);
            sj[j] = z;
        }

        float t[4][4];
        #pragma unroll
        for (int j = 0; j < 4; ++j)
            #pragma unroll
            for (int r = 0; r < 4; ++r) t[j][r] = sj[j][r] * sc;

        if (kb0 + 63 > q0) {  // tile may cross diagonal (or pad past nk): causal mask
            #pragma unroll
            for (int j = 0; j < 4; ++j)
                #pragma unroll
                for (int r = 0; r < 4; ++r)
                    if (kb0 + j * 16 + lr > q0 + lg * 4 + r) t[j][r] = -1e30f;
        }

        // row max over 64 keys
        float mx[4];
        #pragma unroll
        for (int r = 0; r < 4; ++r)
            mx[r] = fmaxf(fmaxf(t[0][r], t[1][r]), fmaxf(t[2][r], t[3][r]));
        #pragma unroll
        for (int off = 1; off < 16; off <<= 1)
            #pragma unroll
            for (int r = 0; r < 4; ++r) mx[r] = fmaxf(mx[r], __shfl_xor(mx[r], off));

        float p[4][4], rs[4], so[4];
        #pragma unroll
        for (int r = 0; r < 4; ++r) {
            const float nm = fmaxf(m[r], mx[r]);
            so[r] = __builtin_exp2f(m[r] - nm);   // m=-inf first iter -> 0
            m[r] = nm;
            float a = 0.f;
            #pragma unroll
            for (int j = 0; j < 4; ++j) { p[j][r] = __builtin_exp2f(t[j][r] - nm); a += p[j][r]; }
            rs[r] = a;
        }
        #pragma unroll
        for (int off = 1; off < 16; off <<= 1)
            #pragma unroll
            for (int r = 0; r < 4; ++r) rs[r] += __shfl_xor(rs[r], off);
        #pragma unroll
        for (int r = 0; r < 4; ++r) lsum[r] = lsum[r] * so[r] + rs[r];
        #pragma unroll
        for (int n = 0; n < 4; ++n)
            #pragma unroll
            for (int r = 0; r < 4; ++r) acc[n][r] *= so[r];

        // P (16x64) -> LDS bf16, re-read as A-fragments (single wave: fence, no barrier)
        #pragma unroll
        for (int j = 0; j < 4; ++j)
            #pragma unroll
            for (int r = 0; r < 4; ++r)
                p_lds[lg * 4 + r][j * 16 + lr] = (__bf16)p[j][r];
        asm volatile("s_waitcnt lgkmcnt(0)" ::: "memory");
        const bf16x8 pa0 = *(const bf16x8*)&p_lds[lr][lg * 8];
        const bf16x8 pa1 = *(const bf16x8*)&p_lds[lr][32 + lg * 8];
        #pragma unroll
        for (int n = 0; n < 4; ++n) {
            bf16x8 vf0 = *(const bf16x8*)&vb[(size_t)(n * 16 + lr) * NROW + kb0 + lg * 8];
            acc[n] = __builtin_amdgcn_mfma_f32_16x16x32_bf16(pa0, vf0, acc[n], 0, 0, 0);
            bf16x8 vf1 = *(const bf16x8*)&vb[(size_t)(n * 16 + lr) * NROW + kb0 + 32 + lg * 8];
            acc[n] = __builtin_amdgcn_mfma_f32_16x16x32_bf16(pa1, vf1, acc[n], 0, 0, 0);
        }
        asm volatile("" ::: "memory");
    }

    // epilogue: unnormalized O partial + per-row m/l (l=0 for fully-masked rows)
    float* Op = opart + ((size_t)s * KSPLIT + split) * (16 * 64);
    #pragma unroll
    for (int n = 0; n < 4; ++n)
        #pragma unroll
        for (int r = 0; r < 4; ++r)
            Op[(size_t)(lg * 4 + r) * 64 + n * 16 + lr] = acc[n][r];
    if (lr == 0) {
        #pragma unroll
        for (int r = 0; r < 4; ++r) {
            const float lout = (m[r] > -1e29f) ? lsum[r] : 0.f;
            mlp[lg * 4 + r]      = m[r];
            mlp[16 + lg * 4 + r] = lout;
        }
    }
}

// ---------------- combine split-K partials ----------------
// grid: NROW*HD/256 blocks x 256 thr; one thread per output element.
__global__ __launch_bounds__(256)
void reduce_kernel(const float* __restrict__ opart, const float* __restrict__ ml,
                   float* __restrict__ out) {
    const int e   = blockIdx.x * 256 + threadIdx.x;
    const int col = e & 63;
    const int row = e >> 6;                 // global row = b*SEQ + sq
    const int b   = row >> 12;
    const int sq  = row & (SEQ - 1);
    const int s   = ((sq >> 4) << 2) | b;
    const int r   = sq & 15;
    const int nk  = (sq & ~15) + 16;
    const int chunk = ((nk + KSPLIT * 64 - 1) / (KSPLIT * 64)) * 64;
    const int nsp   = (nk + chunk - 1) / chunk;

    float M = -INFINITY, ls = 0.f, o = 0.f;
    for (int sp = 0; sp < nsp; ++sp) {
        const float* mlp = ml + ((size_t)s * KSPLIT + sp) * 32;
        const float lv = mlp[16 + r];
        if (lv > 0.f) {
            const float mv = mlp[r];
            const float nm = fmaxf(M, mv);
            const float f0 = __builtin_exp2f(M - nm);   // M=-inf first -> 0
            const float f1 = __builtin_exp2f(mv - nm);
            const float ov = opart[((size_t)s * KSPLIT + sp) * (16 * 64) + (size_t)r * 64 + col];
            o  = o * f0 + f1 * ov;
            ls = ls * f0 + f1 * lv;
            M = nm;
        }
    }
    out[e] = o / ls;
}

extern "C" void kernel_launch(void* const* d_in, const int* in_sizes, int n_in,
                              void* d_out, int out_size, void* d_ws, size_t ws_size,
                              hipStream_t stream) {
    const float* hidden = (const float*)d_in[0];
    const float* Wq = (const float*)d_in[1];
    const float* bq = (const float*)d_in[2];
    const float* Wk = (const float*)d_in[3];
    const float* bk = (const float*)d_in[4];
    const float* Wv = (const float*)d_in[5];
    const float* bv = (const float*)d_in[6];

    __bf16* qbuf  = (__bf16*)d_ws;                     // [NROW][64]
    __bf16* kbuf  = qbuf + (size_t)NROW * HD;          // [NROW][64]
    __bf16* vtbuf = kbuf + (size_t)NROW * HD;          // [64][NROW] (V transposed)
    __bf16* wT    = vtbuf + (size_t)NROW * HD;         // [192][768]
    float*  opart = (float*)(wT + (size_t)192 * EMBED);            // [NSTRIP][KSPLIT][16][64]
    float*  ml    = opart + (size_t)NSTRIP * KSPLIT * 16 * 64;     // [NSTRIP][KSPLIT][32]

    wconv_kernel<<<(192 * EMBED) / 256, 256, 0, stream>>>(Wq, Wk, Wv, wT);

    qkv_gemm_kernel<<<NROW / 16, 64, 0, stream>>>(
        hidden, wT, bq, bk, bv, qbuf, kbuf, vtbuf);

    attn_kernel<<<NSTRIP * KSPLIT, 64, 0, stream>>>(
        qbuf, kbuf, vtbuf, opart, ml);

    reduce_kernel<<<(NROW * HD) / 256, 256, 0, stream>>>(opart, ml, (float*)d_out);
}